// Round 5
// baseline (1644.756 us; speedup 1.0000x reference)
//
#include <hip/hip_runtime.h>
#include <stdint.h>

#define DEV static __device__ __forceinline__

typedef int v4i __attribute__((ext_vector_type(4)));
typedef short v8s __attribute__((ext_vector_type(8)));
typedef float v4f __attribute__((ext_vector_type(4)));

constexpr int B_T   = 8192;
constexpr int IN_D  = 1024;
constexpr int H1D   = 2048;
constexpr int H2D   = 2048;
constexpr int CDIM  = 1000;
constexpr int NEXP  = 8;
constexpr int RHD   = 512;
constexpr float QBF  = 127.0f;
constexpr float EPSF = 1e-5f;
constexpr int NSLOT = 2 * B_T;
constexpr int MAXT  = 72;            // 256-row tiles: 16384/256 + 8 remainders
constexpr float GAP_DELTA = 2e-3f;   // top2/top3 logit-gap guard threshold

// ---------------- global->LDS direct load (16B/lane, wave-uniform LDS base) ----
DEV void load_lds16(const void* g, void* l) {
  __builtin_amdgcn_global_load_lds(
      (const __attribute__((address_space(1))) uint32_t*)(uintptr_t)g,
      (__attribute__((address_space(3))) uint32_t*)(uint32_t)(uintptr_t)l,
      16, 0, 0);
}

DEV uint32_t pack4(float a, float b, float c, float d, float s) {
  int q0 = (int)rintf(a * s); q0 = q0 > 127 ? 127 : (q0 < -127 ? -127 : q0);
  int q1 = (int)rintf(b * s); q1 = q1 > 127 ? 127 : (q1 < -127 ? -127 : q1);
  int q2 = (int)rintf(c * s); q2 = q2 > 127 ? 127 : (q2 < -127 ? -127 : q2);
  int q3 = (int)rintf(d * s); q3 = q3 > 127 ? 127 : (q3 < -127 ? -127 : q3);
  return (uint32_t)(uint8_t)q0 | ((uint32_t)(uint8_t)q1 << 8) |
         ((uint32_t)(uint8_t)q2 << 16) | ((uint32_t)(uint8_t)q3 << 24);
}

DEV uint16_t f2bf(float f) {
  uint32_t u = __float_as_uint(f);
  return (uint16_t)((u + 0x7FFFu + ((u >> 16) & 1u)) >> 16);
}
DEV float bf2f(uint16_t h) { return __uint_as_float((uint32_t)h << 16); }

// ---------------- weight |.| mean reduction (deterministic two-stage) ----------
__global__ __launch_bounds__(256) void wabs_reduce(const float* __restrict__ W,
                                                   long perExpert, int tbase,
                                                   double* __restrict__ partial) {
  int e = blockIdx.y;
  const float4* base = (const float4*)(W + (long)e * perExpert);
  long n4 = perExpert >> 2;
  double s = 0.0;
  for (long i = (long)blockIdx.x * 256 + threadIdx.x; i < n4; i += 32L * 256L) {
    float4 v = base[i];
    s += (double)fabsf(v.x) + (double)fabsf(v.y) + (double)fabsf(v.z) + (double)fabsf(v.w);
  }
  __shared__ double red[256];
  red[threadIdx.x] = s;
  __syncthreads();
  for (int st = 128; st > 0; st >>= 1) {
    if ((int)threadIdx.x < st) red[threadIdx.x] += red[threadIdx.x + st];
    __syncthreads();
  }
  if (threadIdx.x == 0) partial[(long)(tbase + e) * 32 + blockIdx.x] = red[0];
}

__global__ void finalize_scales(const double* __restrict__ partial, float* __restrict__ swf) {
  int t = threadIdx.x;
  if (t >= 24) return;
  double s = 0.0;
  for (int i = 0; i < 32; ++i) s += partial[t * 32 + i];
  long cnt = (t < 8) ? (long)H1D * IN_D : (t < 16) ? (long)H2D * H1D : (long)CDIM * H2D;
  float mean = (float)(s / (double)cnt);
  swf[t] = fmaxf(mean, EPSF);
}

// ---------------- ternary weight quantization --------------------------------
__global__ __launch_bounds__(256) void wquant(const float* __restrict__ W,
                                              int8_t* __restrict__ Wq,
                                              const float* __restrict__ swf, int tbase,
                                              long perExpert, long total4) {
  long i = (long)blockIdx.x * 256 + threadIdx.x;
  if (i >= total4) return;
  long e = (i * 4) / perExpert;
  float s = swf[tbase + (int)e];
  float4 v = ((const float4*)W)[i];
  float t0 = fminf(fmaxf(rintf(v.x / s), -1.f), 1.f);
  float t1 = fminf(fmaxf(rintf(v.y / s), -1.f), 1.f);
  float t2 = fminf(fmaxf(rintf(v.z / s), -1.f), 1.f);
  float t3 = fminf(fmaxf(rintf(v.w / s), -1.f), 1.f);
  uint32_t p = (uint32_t)(uint8_t)(int8_t)t0 | ((uint32_t)(uint8_t)(int8_t)t1 << 8) |
               ((uint32_t)(uint8_t)(int8_t)t2 << 16) | ((uint32_t)(uint8_t)(int8_t)t3 << 24);
  ((uint32_t*)Wq)[i] = p;
}

// ---------------- per-row activation quantization ----------------------------
template <int WIDTH>
__global__ __launch_bounds__(256) void actquant(const float* __restrict__ X,
                                                int8_t* __restrict__ Xq,
                                                float* __restrict__ rcp_out) {
  constexpr int PT = WIDTH / 1024;
  const int row = blockIdx.x;
  const int tid = threadIdx.x;
  const float4* src = (const float4*)(X + (size_t)row * WIDTH);
  float4 v[PT];
  float mx = 0.f;
#pragma unroll
  for (int p = 0; p < PT; ++p) {
    v[p] = src[tid * PT + p];
    mx = fmaxf(mx, fmaxf(fmaxf(fabsf(v[p].x), fabsf(v[p].y)),
                         fmaxf(fabsf(v[p].z), fabsf(v[p].w))));
  }
#pragma unroll
  for (int m = 1; m < 64; m <<= 1) mx = fmaxf(mx, __shfl_xor(mx, m));
  __shared__ float wmax[4];
  const int lane = tid & 63, w = tid >> 6;
  if (lane == 0) wmax[w] = mx;
  __syncthreads();
  mx = fmaxf(fmaxf(wmax[0], wmax[1]), fmaxf(wmax[2], wmax[3]));
  const float M = fmaxf(mx, EPSF);
  const float s = QBF / M;
  uint32_t* dst = (uint32_t*)(Xq + (size_t)row * WIDTH);
#pragma unroll
  for (int p = 0; p < PT; ++p)
    dst[tid * PT + p] = pack4(v[p].x, v[p].y, v[p].z, v[p].w, s);
  if (tid == 0) rcp_out[row] = M / QBF;
}

// ---------------- fp32 -> bf16 hi/lo split ------------------------------------
__global__ __launch_bounds__(256) void split_bf16(const float* __restrict__ src,
                                                  uint16_t* __restrict__ hi,
                                                  uint16_t* __restrict__ lo, long n4) {
  long i = (long)blockIdx.x * 256 + threadIdx.x;
  if (i >= n4) return;
  float4 v = ((const float4*)src)[i];
  ushort4 h, l;
  float f[4] = {v.x, v.y, v.z, v.w};
  uint16_t hh[4], ll[4];
#pragma unroll
  for (int j = 0; j < 4; ++j) {
    hh[j] = f2bf(f[j]);
    ll[j] = f2bf(f[j] - bf2f(hh[j]));
  }
  h.x = hh[0]; h.y = hh[1]; h.z = hh[2]; h.w = hh[3];
  l.x = ll[0]; l.y = ll[1]; l.z = ll[2]; l.w = ll[3];
  ((ushort4*)hi)[i] = h;
  ((ushort4*)lo)[i] = l;
}

// ---------------- router GEMM1: bf16x3 split MFMA (h = relu(x@Wr1^T+b)) ------
__global__ __launch_bounds__(256, 1) void router_mfma(
    const uint16_t* __restrict__ xh, const uint16_t* __restrict__ xl,
    const uint16_t* __restrict__ wh, const uint16_t* __restrict__ wl,
    const float* __restrict__ br1, float* __restrict__ h) {
  __shared__ __align__(16) int8_t smem[2][65536];
  const int tid = threadIdx.x;
  const int lane = tid & 63, wid = tid >> 6;
  const int wm = wid >> 1, wn = wid & 1;
  const int row0 = blockIdx.x * 128, col0 = blockIdx.y * 128;

  const uint16_t* mats[4] = {xh, xl, wh, wl};
  const int rb[4] = {row0, row0, col0, col0};
  const uint8_t* src[16];
#pragma unroll
  for (int R = 0; R < 4; ++R)
#pragma unroll
    for (int i = 0; i < 4; ++i) {
      int p = i * 256 + tid;
      int r = p >> 3, c = p & 7;
      int cs = c ^ (r & 7);
      src[R * 4 + i] = (const uint8_t*)mats[R] + ((long)(rb[R] + r) * IN_D + cs * 8) * 2;
    }

  v4f acc[4][4] = {};
  auto stage = [&](int buf, int kt) {
#pragma unroll
    for (int R = 0; R < 4; ++R)
#pragma unroll
      for (int i = 0; i < 4; ++i)
        load_lds16(src[R * 4 + i] + kt * 128,
                   &smem[buf][R * 16384 + i * 4096 + wid * 1024]);
  };

  stage(0, 0);
  asm volatile("s_waitcnt vmcnt(0)" ::: "memory");
  __syncthreads();
  int buf = 0;
  for (int kt = 0; kt < 16; ++kt) {
    if (kt + 1 < 16) stage(buf ^ 1, kt + 1);
#pragma unroll
    for (int ks = 0; ks < 2; ++ks) {
      v8s ah[4], al[4], bh[4], bl[4];
#pragma unroll
      for (int m = 0; m < 4; ++m) {
        int r = wm * 64 + m * 16 + (lane & 15);
        int ch = (ks * 4 + (lane >> 4)) ^ (r & 7);
        ah[m] = *(const v8s*)&smem[buf][r * 128 + ch * 16];
        al[m] = *(const v8s*)&smem[buf][16384 + r * 128 + ch * 16];
      }
#pragma unroll
      for (int n = 0; n < 4; ++n) {
        int r = wn * 64 + n * 16 + (lane & 15);
        int ch = (ks * 4 + (lane >> 4)) ^ (r & 7);
        bh[n] = *(const v8s*)&smem[buf][32768 + r * 128 + ch * 16];
        bl[n] = *(const v8s*)&smem[buf][49152 + r * 128 + ch * 16];
      }
#pragma unroll
      for (int m = 0; m < 4; ++m)
#pragma unroll
        for (int n = 0; n < 4; ++n) {
          acc[m][n] = __builtin_amdgcn_mfma_f32_16x16x32_bf16(ah[m], bh[n], acc[m][n], 0, 0, 0);
          acc[m][n] = __builtin_amdgcn_mfma_f32_16x16x32_bf16(ah[m], bl[n], acc[m][n], 0, 0, 0);
          acc[m][n] = __builtin_amdgcn_mfma_f32_16x16x32_bf16(al[m], bh[n], acc[m][n], 0, 0, 0);
        }
    }
    asm volatile("s_waitcnt vmcnt(0)" ::: "memory");
    __syncthreads();
    buf ^= 1;
  }

  const int rbase = (lane >> 4) * 4;
  const int cfr = lane & 15;
#pragma unroll
  for (int m = 0; m < 4; ++m)
#pragma unroll
    for (int rg = 0; rg < 4; ++rg) {
      int row = row0 + wm * 64 + m * 16 + rbase + rg;
#pragma unroll
      for (int n = 0; n < 4; ++n) {
        int col = col0 + wn * 64 + n * 16 + cfr;
        h[(long)row * RHD + col] = fmaxf(acc[m][n][rg] + br1[col], 0.f);
      }
    }
}

// ---------------- router stage2: logits + softmax + top-2 + gap guard --------
__global__ __launch_bounds__(256) void router_stage2(const float* __restrict__ h,
                                                     const float* __restrict__ Wr2,
                                                     const float* __restrict__ br2,
                                                     float* __restrict__ probs,
                                                     int* __restrict__ idxg,
                                                     float* __restrict__ gvg,
                                                     int* __restrict__ scount,
                                                     int* __restrict__ suspects) {
  __shared__ float w2s[NEXP * RHD];
  const int tid = threadIdx.x;
  for (int i = tid; i < NEXP * RHD; i += 256) w2s[i] = Wr2[i];
  __syncthreads();
  const int lane = tid & 63, w = tid >> 6;
  const int b = blockIdx.x * 4 + w;
  const float* hrow = h + (long)b * RHD;
  float4 v0 = *(const float4*)&hrow[lane * 8];
  float4 v1 = *(const float4*)&hrow[lane * 8 + 4];
  float hr[8] = {v0.x, v0.y, v0.z, v0.w, v1.x, v1.y, v1.z, v1.w};
  float lg[8];
#pragma unroll
  for (int e = 0; e < 8; ++e) {
    float p = 0.f;
#pragma unroll
    for (int j = 0; j < 8; ++j) p = fmaf(hr[j], w2s[e * RHD + lane * 8 + j], p);
#pragma unroll
    for (int m = 1; m < 64; m <<= 1) p += __shfl_xor(p, m);
    lg[e] = p + br2[e];
  }
  if (lane == 0) {
    float mx = lg[0];
#pragma unroll
    for (int e = 1; e < 8; ++e) mx = fmaxf(mx, lg[e]);
    float ex[8], sum = 0.f;
#pragma unroll
    for (int e = 0; e < 8; ++e) { ex[e] = expf(lg[e] - mx); sum += ex[e]; }
#pragma unroll
    for (int e = 0; e < 8; ++e) probs[(long)b * 8 + e] = ex[e] / sum;
    int i0 = 0; float b0 = lg[0];
#pragma unroll
    for (int e = 1; e < 8; ++e) if (lg[e] > b0) { b0 = lg[e]; i0 = e; }
    int i1 = -1; float b1v = -3.4e38f;
#pragma unroll
    for (int e = 0; e < 8; ++e) if (e != i0 && lg[e] > b1v) { b1v = lg[e]; i1 = e; }
    float b2v = -3.4e38f;
#pragma unroll
    for (int e = 0; e < 8; ++e) if (e != i0 && e != i1 && lg[e] > b2v) b2v = lg[e];
    idxg[b * 2 + 0] = i0; idxg[b * 2 + 1] = i1;
    gvg[b * 2 + 0] = ex[i0] / sum; gvg[b * 2 + 1] = ex[i1] / sum;
    if (b1v - b2v < GAP_DELTA) {
      int p = atomicAdd(scount, 1);
      if (p < B_T) suspects[p] = b;
    }
  }
}

// ---------------- exact fp32 recompute for gap-guard suspects ----------------
__global__ __launch_bounds__(256) void router_fixup(const float* __restrict__ x,
                                                    const float* __restrict__ Wr1,
                                                    const float* __restrict__ br1,
                                                    const float* __restrict__ Wr2,
                                                    const float* __restrict__ br2,
                                                    const int* __restrict__ suspects,
                                                    const int* __restrict__ scount,
                                                    float* __restrict__ probs,
                                                    int* __restrict__ idxg,
                                                    float* __restrict__ gvg) {
  __shared__ float xr[IN_D];
  __shared__ float hr[RHD];
  __shared__ float lgs[NEXP];
  const int n = *scount;
  const int tid = threadIdx.x;
  for (int s = blockIdx.x; s < n && s < B_T; s += 128) {
    const int b = suspects[s];
    __syncthreads();
    for (int i = tid; i < IN_D; i += 256) xr[i] = x[(long)b * IN_D + i];
    __syncthreads();
    {
      const int c0 = tid * 2, c1 = tid * 2 + 1;
      const float* w0 = Wr1 + (long)c0 * IN_D;
      const float* w1 = Wr1 + (long)c1 * IN_D;
      float a0 = 0.f, a1 = 0.f;
      for (int k = 0; k < IN_D; ++k) {
        float xv = xr[k];
        a0 = fmaf(xv, w0[k], a0);
        a1 = fmaf(xv, w1[k], a1);
      }
      hr[c0] = fmaxf(a0 + br1[c0], 0.f);
      hr[c1] = fmaxf(a1 + br1[c1], 0.f);
    }
    __syncthreads();
    if (tid < NEXP) {
      const float* w2 = Wr2 + (long)tid * RHD;
      float a = 0.f;
      for (int k = 0; k < RHD; ++k) a = fmaf(hr[k], w2[k], a);
      lgs[tid] = a + br2[tid];
    }
    __syncthreads();
    if (tid == 0) {
      float lg[8];
#pragma unroll
      for (int e = 0; e < 8; ++e) lg[e] = lgs[e];
      float mx = lg[0];
#pragma unroll
      for (int e = 1; e < 8; ++e) mx = fmaxf(mx, lg[e]);
      float ex[8], sum = 0.f;
#pragma unroll
      for (int e = 0; e < 8; ++e) { ex[e] = expf(lg[e] - mx); sum += ex[e]; }
#pragma unroll
      for (int e = 0; e < 8; ++e) probs[(long)b * 8 + e] = ex[e] / sum;
      int i0 = 0; float b0 = lg[0];
#pragma unroll
      for (int e = 1; e < 8; ++e) if (lg[e] > b0) { b0 = lg[e]; i0 = e; }
      int i1 = -1; float b1v = -3.4e38f;
#pragma unroll
      for (int e = 0; e < 8; ++e) if (e != i0 && lg[e] > b1v) { b1v = lg[e]; i1 = e; }
      idxg[b * 2 + 0] = i0; idxg[b * 2 + 1] = i1;
      gvg[b * 2 + 0] = ex[i0] / sum; gvg[b * 2 + 1] = ex[i1] / sum;
    }
  }
}

// ---------------- histogram / scan / placement (LDS atomics only) ------------
__global__ __launch_bounds__(256) void hist_block(const int* __restrict__ idxg,
                                                  int* __restrict__ bc) {
  __shared__ int hloc[NEXP];
  const int t = threadIdx.x;
  if (t < NEXP) hloc[t] = 0;
  __syncthreads();
  int a = blockIdx.x * 256 + t;
  atomicAdd(&hloc[idxg[a]], 1);
  __syncthreads();
  if (t < NEXP) bc[blockIdx.x * NEXP + t] = hloc[t];
}

__global__ void scan_all(const int* __restrict__ bc, int* __restrict__ blockbase,
                         int* __restrict__ ntiles, int* __restrict__ te,
                         int* __restrict__ ts, int* __restrict__ tc,
                         float* __restrict__ loss_out) {
  __shared__ int counts[NEXP], basep[NEXP];
  const int t = threadIdx.x;
  if (t < NEXP) {
    int s = 0;
    for (int b = 0; b < 64; ++b) s += bc[b * NEXP + t];
    counts[t] = s;
  }
  __syncthreads();
  if (t == 0) {
    int acc = 0, nb = 0;
    for (int e = 0; e < NEXP; ++e) {
      basep[e] = acc;
      int c = counts[e];
      int nt = (c + 255) >> 8;
      for (int i = 0; i < nt; ++i) {
        te[nb] = e; ts[nb] = acc + i * 256; tc[nb] = min(256, c - i * 256); ++nb;
      }
      acc += c;
    }
    *ntiles = nb;
    *loss_out = 0.f;
  }
  __syncthreads();
  if (t < NEXP) {
    int run = basep[t];
    for (int b = 0; b < 64; ++b) { blockbase[b * NEXP + t] = run; run += bc[b * NEXP + t]; }
  }
}

__global__ __launch_bounds__(256) void place2(const int* __restrict__ idxg,
                                              const int* __restrict__ blockbase,
                                              int* __restrict__ token_list,
                                              int* __restrict__ slotmap) {
  __shared__ int cur[NEXP];
  const int t = threadIdx.x;
  if (t < NEXP) cur[t] = blockbase[blockIdx.x * NEXP + t];
  __syncthreads();
  int a = blockIdx.x * 256 + t;
  int e = idxg[a];
  int pos = atomicAdd(&cur[e], 1);
  token_list[pos] = a >> 1;
  slotmap[a] = pos;
}

// ---------------- int8 ternary MFMA GEMM (256x256 tile, BK=64, 8 waves) ------
// 64KB LDS (2 x 32KB dbuf) -> 2 blocks/CU; counted-vmcnt prefetch across barriers.
template <int KDIM, bool INDIRECT, bool RELU, bool FINAL>
__global__ __launch_bounds__(512, 4) void gemm_i8(
    const int8_t* __restrict__ Aq, const int8_t* __restrict__ Wq,
    const float* __restrict__ swf_layer, const float* __restrict__ rcp_act,
    const float* __restrict__ bias, const int* __restrict__ te,
    const int* __restrict__ ts, const int* __restrict__ tc,
    const int* __restrict__ ntiles_p, const int* __restrict__ token_list,
    float* __restrict__ Yout, int Nvalid) {
  if ((int)blockIdx.x >= *ntiles_p) return;
  extern __shared__ __align__(16) int8_t smem_dyn[];   // 2 x 32KB: [A 16KB | B 16KB]
  const int t = blockIdx.x;
  const int e = te[t], row0 = ts[t], rcount = tc[t];
  const int col0 = blockIdx.y * 256;
  const int tid = threadIdx.x;
  const int lane = tid & 63, wid = tid >> 6;
  const int wm = wid >> 2, wn = wid & 3;     // 2 (M) x 4 (N) waves -> 128x64 each

  // staging: 1024 chunk-positions per matrix (256 rows x 4 chunks of 16B)
  // LDS slot c holds global chunk c ^ ((r>>1)&3)  (pre-swizzled source)
  const int8_t* srcA[2];
  const int8_t* srcB[2];
#pragma unroll
  for (int i = 0; i < 2; ++i) {
    int p = i * 512 + tid;
    int r = p >> 2, c = p & 3;
    int cs = c ^ ((r >> 1) & 3);
    int ar = row0 + min(r, rcount - 1);
    long arow = INDIRECT ? (long)token_list[ar] : (long)ar;
    srcA[i] = Aq + arow * KDIM + cs * 16;
    int br = min(col0 + r, Nvalid - 1);
    srcB[i] = Wq + ((long)e * Nvalid + br) * (long)KDIM + cs * 16;
  }

  auto stage = [&](int buf, int kt) {
#pragma unroll
    for (int i = 0; i < 2; ++i) {
      int off = buf * 32768 + (i * 512 + (wid << 6)) * 16;
      load_lds16(srcA[i] + kt * 64, &smem_dyn[off]);
      load_lds16(srcB[i] + kt * 64, &smem_dyn[16384 + off]);
    }
  };

  v4i acc[8][4] = {};
  constexpr int KT = KDIM / 64;
  stage(0, 0);
  asm volatile("s_waitcnt vmcnt(0)" ::: "memory");
  __builtin_amdgcn_s_barrier();
  int buf = 0;
  for (int kt = 0; kt < KT; ++kt) {
    if (kt + 1 < KT) {
      stage(buf ^ 1, kt + 1);                       // 4 loads stay in flight
      asm volatile("s_waitcnt vmcnt(4)" ::: "memory");
    } else {
      asm volatile("s_waitcnt vmcnt(0)" ::: "memory");
    }
    __builtin_amdgcn_s_barrier();
    __builtin_amdgcn_sched_barrier(0);
    const int8_t* As = &smem_dyn[buf * 32768];
    const int8_t* Bs = &smem_dyn[buf * 32768 + 16384];
    v4i bv[4];
#pragma unroll
    for (int n = 0; n < 4; ++n) {
      int r = wn * 64 + n * 16 + (lane & 15);
      int cs = (lane >> 4) ^ ((r >> 1) & 3);
      bv[n] = *(const v4i*)&Bs[r * 64 + cs * 16];
    }
#pragma unroll
    for (int m = 0; m < 8; ++m) {
      int r = wm * 128 + m * 16 + (lane & 15);
      int cs = (lane >> 4) ^ ((r >> 1) & 3);
      v4i av = *(const v4i*)&As[r * 64 + cs * 16];
#pragma unroll
      for (int n = 0; n < 4; ++n)
        acc[m][n] = __builtin_amdgcn_mfma_i32_16x16x64_i8(av, bv[n], acc[m][n], 0, 0, 0);
    }
    __builtin_amdgcn_sched_barrier(0);
    __builtin_amdgcn_s_barrier();
    buf ^= 1;
  }

  const float sw = swf_layer[e];
  const int rbase = (lane >> 4) * 4;
  const int cfr = lane & 15;
  const float* bias_e = bias + (long)e * Nvalid;
#pragma unroll
  for (int m = 0; m < 8; ++m) {
#pragma unroll
    for (int rg = 0; rg < 4; ++rg) {
      int trow = wm * 128 + m * 16 + rbase + rg;
      if (trow >= rcount) continue;
      int slot = row0 + trow;
      float rcp = rcp_act[INDIRECT ? token_list[slot] : slot];
      float dq = sw * rcp;
      if (!FINAL) {
        float* yrow = Yout + (long)slot * 2048;
#pragma unroll
        for (int n = 0; n < 4; ++n) {
          int o = col0 + wn * 64 + n * 16 + cfr;
          float v = (float)acc[m][n][rg] * dq + bias_e[o];
          if (RELU) v = fmaxf(v, 0.f);
          yrow[o] = v;
        }
      } else {
        float* zrow = Yout + (long)slot * 1024;
#pragma unroll
        for (int n = 0; n < 4; ++n) {
          int o = col0 + wn * 64 + n * 16 + cfr;
          float bb = bias_e[min(o, Nvalid - 1)];
          zrow[o] = (float)acc[m][n][rg] * dq + bb;
        }
      }
    }
  }
}

// ---------------- gate-weighted combine: out[b] = g0*z[s0] + g1*z[s1] --------
__global__ __launch_bounds__(256) void combine(const float* __restrict__ z,
                                               const int* __restrict__ slotmap,
                                               const float* __restrict__ gvg,
                                               float* __restrict__ out) {
  const int b = blockIdx.x;
  const int c = threadIdx.x;
  if (c >= 250) return;
  const int s0 = slotmap[b * 2], s1 = slotmap[b * 2 + 1];
  const float g0 = gvg[b * 2] * 0.5f, g1 = gvg[b * 2 + 1] * 0.5f;
  float4 a = *(const float4*)(z + (long)s0 * 1024 + c * 4);
  float4 q = *(const float4*)(z + (long)s1 * 1024 + c * 4);
  float4 o = {g0 * a.x + g1 * q.x, g0 * a.y + g1 * q.y,
              g0 * a.z + g1 * q.z, g0 * a.w + g1 * q.w};
  *(float4*)(out + (long)b * CDIM + c * 4) = o;
}

// ---------------- host launcher ----------------------------------------------
extern "C" void kernel_launch(void* const* d_in, const int* in_sizes, int n_in,
                              void* d_out, int out_size, void* d_ws, size_t ws_size,
                              hipStream_t stream) {
  const float* x   = (const float*)d_in[0];
  const float* Wr1 = (const float*)d_in[1];
  const float* br1 = (const float*)d_in[2];
  const float* Wr2 = (const float*)d_in[3];
  const float* br2 = (const float*)d_in[4];
  const float* W1  = (const float*)d_in[5];
  const float* b1  = (const float*)d_in[6];
  const float* W2  = (const float*)d_in[7];
  const float* b2  = (const float*)d_in[8];
  const float* W3  = (const float*)d_in[9];
  const float* b3  = (const float*)d_in[10];
  float* out = (float*)d_out;
  char* ws = (char*)d_ws;

  size_t off = 0;
  auto alloc = [&](size_t sz) { size_t r = off; off = (off + sz + 255) & ~(size_t)255; return r; };
  size_t O_META  = alloc(8192);
  size_t O_SUSP  = alloc(B_T * sizeof(int));
  size_t O_PART  = alloc(24 * 32 * sizeof(double));
  size_t O_SWF   = alloc(24 * sizeof(float));
  size_t O_RCPX  = alloc(B_T * sizeof(float));
  size_t O_IDX   = alloc(B_T * 2 * sizeof(int));
  size_t O_GVG   = alloc(B_T * 2 * sizeof(float));
  size_t O_TLIST = alloc(NSLOT * sizeof(int));
  size_t O_SLOT  = alloc(B_T * 2 * sizeof(int));
  size_t O_S1    = alloc(NSLOT * sizeof(float));
  size_t O_S2    = alloc(NSLOT * sizeof(float));
  size_t O_XQ    = alloc((size_t)B_T * IN_D);
  size_t O_WQ1   = alloc((size_t)NEXP * H1D * IN_D);
  size_t O_WQ2   = alloc((size_t)NEXP * H2D * H1D);
  size_t O_WQ3   = alloc((size_t)NEXP * CDIM * H2D);
  size_t O_YQ    = alloc((size_t)NSLOT * 2048);
  size_t O_YBIG  = alloc((size_t)NSLOT * 2048 * sizeof(float));
  (void)ws_size; (void)in_sizes; (void)n_in;

  int*    te     = (int*)(ws + O_META);
  int*    tsv    = te + 144;
  int*    tcv    = tsv + 144;
  int*    ntiles = tcv + 144;
  int*    bc     = ntiles + 4;          // 64*8
  int*    bbase  = bc + 512;            // 64*8
  int*    scount = bbase + 512;
  int*    susp   = (int*)(ws + O_SUSP);
  double* part   = (double*)(ws + O_PART);
  float*  swf    = (float*)(ws + O_SWF);
  float*  rcpx   = (float*)(ws + O_RCPX);
  int*    idxg   = (int*)(ws + O_IDX);
  float*  gvg    = (float*)(ws + O_GVG);
  int*    tlist  = (int*)(ws + O_TLIST);
  int*    slotmap= (int*)(ws + O_SLOT);
  float*  s1     = (float*)(ws + O_S1);
  float*  s2     = (float*)(ws + O_S2);
  int8_t* Xq     = (int8_t*)(ws + O_XQ);
  int8_t* wq1    = (int8_t*)(ws + O_WQ1);
  int8_t* wq2    = (int8_t*)(ws + O_WQ2);
  int8_t* wq3    = (int8_t*)(ws + O_WQ3);
  int8_t* Yq     = (int8_t*)(ws + O_YQ);
  float*  Ybig   = (float*)(ws + O_YBIG);   // router h; split bufs; activations; z
  float*  h      = Ybig;
  float*  zbuf   = Ybig;

  // bf16 split buffers live in the (currently dead) tail of Ybig
  char* ybytes = (char*)Ybig;
  uint16_t* xh = (uint16_t*)(ybytes + (20l << 20));
  uint16_t* xl = (uint16_t*)(ybytes + (40l << 20));
  uint16_t* wh = (uint16_t*)(ybytes + (60l << 20));
  uint16_t* wl = (uint16_t*)(ybytes + (62l << 20));

  hipMemsetAsync(ws + O_META, 0, 8192, stream);

  // weight scales + ternary quant
  wabs_reduce<<<dim3(32, 8), 256, 0, stream>>>(W1, (long)H1D * IN_D, 0, part);
  wabs_reduce<<<dim3(32, 8), 256, 0, stream>>>(W2, (long)H2D * H1D, 8, part);
  wabs_reduce<<<dim3(32, 8), 256, 0, stream>>>(W3, (long)CDIM * H2D, 16, part);
  finalize_scales<<<1, 64, 0, stream>>>(part, swf);
  wquant<<<16384, 256, 0, stream>>>(W1, wq1, swf, 0, (long)H1D * IN_D, 4194304L);
  wquant<<<32768, 256, 0, stream>>>(W2, wq2, swf, 8, (long)H2D * H1D, 8388608L);
  wquant<<<16000, 256, 0, stream>>>(W3, wq3, swf, 16, (long)CDIM * H2D, 4096000L);

  // activation quant of x
  actquant<IN_D><<<B_T, 256, 0, stream>>>(x, Xq, rcpx);

  // router: split -> bf16x3 MFMA -> stage2 -> gap-guard fixup
  split_bf16<<<8192, 256, 0, stream>>>(x, xh, xl, (long)B_T * IN_D / 4);
  split_bf16<<<512, 256, 0, stream>>>(Wr1, wh, wl, (long)RHD * IN_D / 4);
  router_mfma<<<dim3(B_T / 128, RHD / 128), 256, 0, stream>>>(xh, xl, wh, wl, br1, h);
  router_stage2<<<B_T / 4, 256, 0, stream>>>(h, Wr2, br2, out + (size_t)B_T * CDIM,
                                             idxg, gvg, scount, susp);
  router_fixup<<<128, 256, 0, stream>>>(x, Wr1, br1, Wr2, br2, susp, scount,
                                        out + (size_t)B_T * CDIM, idxg, gvg);
  hist_block<<<64, 256, 0, stream>>>(idxg, bc);
  scan_all<<<1, 64, 0, stream>>>(bc, bbase, ntiles, te, tsv, tcv,
                                 out + (size_t)B_T * CDIM + (size_t)B_T * NEXP);
  place2<<<64, 256, 0, stream>>>(idxg, bbase, tlist, slotmap);

  // expert layers (int8 MFMA, 256x256 tiles, 64KB dynamic LDS -> 2 blocks/CU)
  gemm_i8<IN_D, true, true, false><<<dim3(MAXT, H1D / 256), 512, 65536, stream>>>(
      Xq, wq1, swf + 0, rcpx, b1, te, tsv, tcv, ntiles, tlist, Ybig, H1D);
  actquant<2048><<<NSLOT, 256, 0, stream>>>(Ybig, Yq, s1);
  gemm_i8<2048, false, true, false><<<dim3(MAXT, H2D / 256), 512, 65536, stream>>>(
      Yq, wq2, swf + 8, s1, b2, te, tsv, tcv, ntiles, tlist, Ybig, H2D);
  actquant<2048><<<NSLOT, 256, 0, stream>>>(Ybig, Yq, s2);
  gemm_i8<2048, false, false, true><<<dim3(MAXT, 1024 / 256), 512, 65536, stream>>>(
      Yq, wq3, swf + 16, s2, b3, te, tsv, tcv, ntiles, tlist, zbuf, CDIM);

  // gate-weighted combine into d_out
  combine<<<B_T, 256, 0, stream>>>(zbuf, slotmap, gvg, out);
}

// Round 6
// 679.453 us; speedup vs baseline: 2.4207x; 2.4207x over previous
//
#include <hip/hip_runtime.h>
#include <stdint.h>

#define DEV static __device__ __forceinline__

typedef int v4i __attribute__((ext_vector_type(4)));
typedef short v8s __attribute__((ext_vector_type(8)));
typedef float v4f __attribute__((ext_vector_type(4)));

constexpr int B_T   = 8192;
constexpr int IN_D  = 1024;
constexpr int H1D   = 2048;
constexpr int H2D   = 2048;
constexpr int CDIM  = 1000;
constexpr int NEXP  = 8;
constexpr int RHD   = 512;
constexpr float QBF  = 127.0f;
constexpr float EPSF = 1e-5f;
constexpr int NSLOT = 2 * B_T;
constexpr int MAXT  = 72;            // 256-row tiles: 16384/256 + 8 remainders
constexpr float GAP_DELTA = 2e-3f;   // top2/top3 logit-gap guard threshold

// ---------------- global->LDS direct load (16B/lane, wave-uniform LDS base) ----
DEV void load_lds16(const void* g, void* l) {
  __builtin_amdgcn_global_load_lds(
      (const __attribute__((address_space(1))) uint32_t*)(uintptr_t)g,
      (__attribute__((address_space(3))) uint32_t*)(uint32_t)(uintptr_t)l,
      16, 0, 0);
}

DEV uint32_t pack4(float a, float b, float c, float d, float s) {
  int q0 = (int)rintf(a * s); q0 = q0 > 127 ? 127 : (q0 < -127 ? -127 : q0);
  int q1 = (int)rintf(b * s); q1 = q1 > 127 ? 127 : (q1 < -127 ? -127 : q1);
  int q2 = (int)rintf(c * s); q2 = q2 > 127 ? 127 : (q2 < -127 ? -127 : q2);
  int q3 = (int)rintf(d * s); q3 = q3 > 127 ? 127 : (q3 < -127 ? -127 : q3);
  return (uint32_t)(uint8_t)q0 | ((uint32_t)(uint8_t)q1 << 8) |
         ((uint32_t)(uint8_t)q2 << 16) | ((uint32_t)(uint8_t)q3 << 24);
}

DEV uint16_t f2bf(float f) {
  uint32_t u = __float_as_uint(f);
  return (uint16_t)((u + 0x7FFFu + ((u >> 16) & 1u)) >> 16);
}
DEV float bf2f(uint16_t h) { return __uint_as_float((uint32_t)h << 16); }

// ---------------- weight |.| mean reduction (deterministic two-stage) ----------
__global__ __launch_bounds__(256) void wabs_reduce(const float* __restrict__ W,
                                                   long perExpert, int tbase,
                                                   double* __restrict__ partial) {
  int e = blockIdx.y;
  const float4* base = (const float4*)(W + (long)e * perExpert);
  long n4 = perExpert >> 2;
  double s = 0.0;
  for (long i = (long)blockIdx.x * 256 + threadIdx.x; i < n4; i += 32L * 256L) {
    float4 v = base[i];
    s += (double)fabsf(v.x) + (double)fabsf(v.y) + (double)fabsf(v.z) + (double)fabsf(v.w);
  }
  __shared__ double red[256];
  red[threadIdx.x] = s;
  __syncthreads();
  for (int st = 128; st > 0; st >>= 1) {
    if ((int)threadIdx.x < st) red[threadIdx.x] += red[threadIdx.x + st];
    __syncthreads();
  }
  if (threadIdx.x == 0) partial[(long)(tbase + e) * 32 + blockIdx.x] = red[0];
}

__global__ void finalize_scales(const double* __restrict__ partial, float* __restrict__ swf) {
  int t = threadIdx.x;
  if (t >= 24) return;
  double s = 0.0;
  for (int i = 0; i < 32; ++i) s += partial[t * 32 + i];
  long cnt = (t < 8) ? (long)H1D * IN_D : (t < 16) ? (long)H2D * H1D : (long)CDIM * H2D;
  float mean = (float)(s / (double)cnt);
  swf[t] = fmaxf(mean, EPSF);
}

// ---------------- ternary weight quantization --------------------------------
__global__ __launch_bounds__(256) void wquant(const float* __restrict__ W,
                                              int8_t* __restrict__ Wq,
                                              const float* __restrict__ swf, int tbase,
                                              long perExpert, long total4) {
  long i = (long)blockIdx.x * 256 + threadIdx.x;
  if (i >= total4) return;
  long e = (i * 4) / perExpert;
  float s = swf[tbase + (int)e];
  float4 v = ((const float4*)W)[i];
  float t0 = fminf(fmaxf(rintf(v.x / s), -1.f), 1.f);
  float t1 = fminf(fmaxf(rintf(v.y / s), -1.f), 1.f);
  float t2 = fminf(fmaxf(rintf(v.z / s), -1.f), 1.f);
  float t3 = fminf(fmaxf(rintf(v.w / s), -1.f), 1.f);
  uint32_t p = (uint32_t)(uint8_t)(int8_t)t0 | ((uint32_t)(uint8_t)(int8_t)t1 << 8) |
               ((uint32_t)(uint8_t)(int8_t)t2 << 16) | ((uint32_t)(uint8_t)(int8_t)t3 << 24);
  ((uint32_t*)Wq)[i] = p;
}

// ---------------- per-row activation quantization ----------------------------
template <int WIDTH>
__global__ __launch_bounds__(256) void actquant(const float* __restrict__ X,
                                                int8_t* __restrict__ Xq,
                                                float* __restrict__ rcp_out) {
  constexpr int PT = WIDTH / 1024;
  const int row = blockIdx.x;
  const int tid = threadIdx.x;
  const float4* src = (const float4*)(X + (size_t)row * WIDTH);
  float4 v[PT];
  float mx = 0.f;
#pragma unroll
  for (int p = 0; p < PT; ++p) {
    v[p] = src[tid * PT + p];
    mx = fmaxf(mx, fmaxf(fmaxf(fabsf(v[p].x), fabsf(v[p].y)),
                         fmaxf(fabsf(v[p].z), fabsf(v[p].w))));
  }
#pragma unroll
  for (int m = 1; m < 64; m <<= 1) mx = fmaxf(mx, __shfl_xor(mx, m));
  __shared__ float wmax[4];
  const int lane = tid & 63, w = tid >> 6;
  if (lane == 0) wmax[w] = mx;
  __syncthreads();
  mx = fmaxf(fmaxf(wmax[0], wmax[1]), fmaxf(wmax[2], wmax[3]));
  const float M = fmaxf(mx, EPSF);
  const float s = QBF / M;
  uint32_t* dst = (uint32_t*)(Xq + (size_t)row * WIDTH);
#pragma unroll
  for (int p = 0; p < PT; ++p)
    dst[tid * PT + p] = pack4(v[p].x, v[p].y, v[p].z, v[p].w, s);
  if (tid == 0) rcp_out[row] = M / QBF;
}

// ---------------- fp32 -> bf16 hi/lo split ------------------------------------
__global__ __launch_bounds__(256) void split_bf16(const float* __restrict__ src,
                                                  uint16_t* __restrict__ hi,
                                                  uint16_t* __restrict__ lo, long n4) {
  long i = (long)blockIdx.x * 256 + threadIdx.x;
  if (i >= n4) return;
  float4 v = ((const float4*)src)[i];
  ushort4 h, l;
  float f[4] = {v.x, v.y, v.z, v.w};
  uint16_t hh[4], ll[4];
#pragma unroll
  for (int j = 0; j < 4; ++j) {
    hh[j] = f2bf(f[j]);
    ll[j] = f2bf(f[j] - bf2f(hh[j]));
  }
  h.x = hh[0]; h.y = hh[1]; h.z = hh[2]; h.w = hh[3];
  l.x = ll[0]; l.y = ll[1]; l.z = ll[2]; l.w = ll[3];
  ((ushort4*)hi)[i] = h;
  ((ushort4*)lo)[i] = l;
}

// ---------------- router GEMM1: bf16x3 split MFMA (h = relu(x@Wr1^T+b)) ------
__global__ __launch_bounds__(256, 1) void router_mfma(
    const uint16_t* __restrict__ xh, const uint16_t* __restrict__ xl,
    const uint16_t* __restrict__ wh, const uint16_t* __restrict__ wl,
    const float* __restrict__ br1, float* __restrict__ h) {
  __shared__ __align__(16) int8_t smem[2][65536];
  const int tid = threadIdx.x;
  const int lane = tid & 63, wid = tid >> 6;
  const int wm = wid >> 1, wn = wid & 1;
  const int row0 = blockIdx.x * 128, col0 = blockIdx.y * 128;

  const uint16_t* mats[4] = {xh, xl, wh, wl};
  const int rb[4] = {row0, row0, col0, col0};
  const uint8_t* src[16];
#pragma unroll
  for (int R = 0; R < 4; ++R)
#pragma unroll
    for (int i = 0; i < 4; ++i) {
      int p = i * 256 + tid;
      int r = p >> 3, c = p & 7;
      int cs = c ^ (r & 7);
      src[R * 4 + i] = (const uint8_t*)mats[R] + ((long)(rb[R] + r) * IN_D + cs * 8) * 2;
    }

  v4f acc[4][4] = {};
  auto stage = [&](int buf, int kt) {
#pragma unroll
    for (int R = 0; R < 4; ++R)
#pragma unroll
      for (int i = 0; i < 4; ++i)
        load_lds16(src[R * 4 + i] + kt * 128,
                   &smem[buf][R * 16384 + i * 4096 + wid * 1024]);
  };

  stage(0, 0);
  asm volatile("s_waitcnt vmcnt(0)" ::: "memory");
  __syncthreads();
  int buf = 0;
  for (int kt = 0; kt < 16; ++kt) {
    if (kt + 1 < 16) stage(buf ^ 1, kt + 1);
#pragma unroll
    for (int ks = 0; ks < 2; ++ks) {
      v8s ah[4], al[4], bh[4], bl[4];
#pragma unroll
      for (int m = 0; m < 4; ++m) {
        int r = wm * 64 + m * 16 + (lane & 15);
        int ch = (ks * 4 + (lane >> 4)) ^ (r & 7);
        ah[m] = *(const v8s*)&smem[buf][r * 128 + ch * 16];
        al[m] = *(const v8s*)&smem[buf][16384 + r * 128 + ch * 16];
      }
#pragma unroll
      for (int n = 0; n < 4; ++n) {
        int r = wn * 64 + n * 16 + (lane & 15);
        int ch = (ks * 4 + (lane >> 4)) ^ (r & 7);
        bh[n] = *(const v8s*)&smem[buf][32768 + r * 128 + ch * 16];
        bl[n] = *(const v8s*)&smem[buf][49152 + r * 128 + ch * 16];
      }
#pragma unroll
      for (int m = 0; m < 4; ++m)
#pragma unroll
        for (int n = 0; n < 4; ++n) {
          acc[m][n] = __builtin_amdgcn_mfma_f32_16x16x32_bf16(ah[m], bh[n], acc[m][n], 0, 0, 0);
          acc[m][n] = __builtin_amdgcn_mfma_f32_16x16x32_bf16(ah[m], bl[n], acc[m][n], 0, 0, 0);
          acc[m][n] = __builtin_amdgcn_mfma_f32_16x16x32_bf16(al[m], bh[n], acc[m][n], 0, 0, 0);
        }
    }
    asm volatile("s_waitcnt vmcnt(0)" ::: "memory");
    __syncthreads();
    buf ^= 1;
  }

  const int rbase = (lane >> 4) * 4;
  const int cfr = lane & 15;
#pragma unroll
  for (int m = 0; m < 4; ++m)
#pragma unroll
    for (int rg = 0; rg < 4; ++rg) {
      int row = row0 + wm * 64 + m * 16 + rbase + rg;
#pragma unroll
      for (int n = 0; n < 4; ++n) {
        int col = col0 + wn * 64 + n * 16 + cfr;
        h[(long)row * RHD + col] = fmaxf(acc[m][n][rg] + br1[col], 0.f);
      }
    }
}

// ---------------- router stage2: logits + softmax + top-2 + gap guard --------
__global__ __launch_bounds__(256) void router_stage2(const float* __restrict__ h,
                                                     const float* __restrict__ Wr2,
                                                     const float* __restrict__ br2,
                                                     float* __restrict__ probs,
                                                     int* __restrict__ idxg,
                                                     float* __restrict__ gvg,
                                                     int* __restrict__ scount,
                                                     int* __restrict__ suspects) {
  __shared__ float w2s[NEXP * RHD];
  const int tid = threadIdx.x;
  for (int i = tid; i < NEXP * RHD; i += 256) w2s[i] = Wr2[i];
  __syncthreads();
  const int lane = tid & 63, w = tid >> 6;
  const int b = blockIdx.x * 4 + w;
  const float* hrow = h + (long)b * RHD;
  float4 v0 = *(const float4*)&hrow[lane * 8];
  float4 v1 = *(const float4*)&hrow[lane * 8 + 4];
  float hr[8] = {v0.x, v0.y, v0.z, v0.w, v1.x, v1.y, v1.z, v1.w};
  float lg[8];
#pragma unroll
  for (int e = 0; e < 8; ++e) {
    float p = 0.f;
#pragma unroll
    for (int j = 0; j < 8; ++j) p = fmaf(hr[j], w2s[e * RHD + lane * 8 + j], p);
#pragma unroll
    for (int m = 1; m < 64; m <<= 1) p += __shfl_xor(p, m);
    lg[e] = p + br2[e];
  }
  if (lane == 0) {
    float mx = lg[0];
#pragma unroll
    for (int e = 1; e < 8; ++e) mx = fmaxf(mx, lg[e]);
    float ex[8], sum = 0.f;
#pragma unroll
    for (int e = 0; e < 8; ++e) { ex[e] = expf(lg[e] - mx); sum += ex[e]; }
#pragma unroll
    for (int e = 0; e < 8; ++e) probs[(long)b * 8 + e] = ex[e] / sum;
    int i0 = 0; float b0 = lg[0];
#pragma unroll
    for (int e = 1; e < 8; ++e) if (lg[e] > b0) { b0 = lg[e]; i0 = e; }
    int i1 = -1; float b1v = -3.4e38f;
#pragma unroll
    for (int e = 0; e < 8; ++e) if (e != i0 && lg[e] > b1v) { b1v = lg[e]; i1 = e; }
    float b2v = -3.4e38f;
#pragma unroll
    for (int e = 0; e < 8; ++e) if (e != i0 && e != i1 && lg[e] > b2v) b2v = lg[e];
    idxg[b * 2 + 0] = i0; idxg[b * 2 + 1] = i1;
    gvg[b * 2 + 0] = ex[i0] / sum; gvg[b * 2 + 1] = ex[i1] / sum;
    if (b1v - b2v < GAP_DELTA) {
      int p = atomicAdd(scount, 1);
      if (p < B_T) suspects[p] = b;
    }
  }
}

// ---------------- exact fp32 recompute for gap-guard suspects ----------------
__global__ __launch_bounds__(256) void router_fixup(const float* __restrict__ x,
                                                    const float* __restrict__ Wr1,
                                                    const float* __restrict__ br1,
                                                    const float* __restrict__ Wr2,
                                                    const float* __restrict__ br2,
                                                    const int* __restrict__ suspects,
                                                    const int* __restrict__ scount,
                                                    float* __restrict__ probs,
                                                    int* __restrict__ idxg,
                                                    float* __restrict__ gvg) {
  __shared__ float xr[IN_D];
  __shared__ float hr[RHD];
  __shared__ float lgs[NEXP];
  const int n = *scount;
  const int tid = threadIdx.x;
  for (int s = blockIdx.x; s < n && s < B_T; s += 128) {
    const int b = suspects[s];
    __syncthreads();
    for (int i = tid; i < IN_D; i += 256) xr[i] = x[(long)b * IN_D + i];
    __syncthreads();
    {
      const int c0 = tid * 2, c1 = tid * 2 + 1;
      const float* w0 = Wr1 + (long)c0 * IN_D;
      const float* w1 = Wr1 + (long)c1 * IN_D;
      float a0 = 0.f, a1 = 0.f;
      for (int k = 0; k < IN_D; ++k) {
        float xv = xr[k];
        a0 = fmaf(xv, w0[k], a0);
        a1 = fmaf(xv, w1[k], a1);
      }
      hr[c0] = fmaxf(a0 + br1[c0], 0.f);
      hr[c1] = fmaxf(a1 + br1[c1], 0.f);
    }
    __syncthreads();
    if (tid < NEXP) {
      const float* w2 = Wr2 + (long)tid * RHD;
      float a = 0.f;
      for (int k = 0; k < RHD; ++k) a = fmaf(hr[k], w2[k], a);
      lgs[tid] = a + br2[tid];
    }
    __syncthreads();
    if (tid == 0) {
      float lg[8];
#pragma unroll
      for (int e = 0; e < 8; ++e) lg[e] = lgs[e];
      float mx = lg[0];
#pragma unroll
      for (int e = 1; e < 8; ++e) mx = fmaxf(mx, lg[e]);
      float ex[8], sum = 0.f;
#pragma unroll
      for (int e = 0; e < 8; ++e) { ex[e] = expf(lg[e] - mx); sum += ex[e]; }
#pragma unroll
      for (int e = 0; e < 8; ++e) probs[(long)b * 8 + e] = ex[e] / sum;
      int i0 = 0; float b0 = lg[0];
#pragma unroll
      for (int e = 1; e < 8; ++e) if (lg[e] > b0) { b0 = lg[e]; i0 = e; }
      int i1 = -1; float b1v = -3.4e38f;
#pragma unroll
      for (int e = 0; e < 8; ++e) if (e != i0 && lg[e] > b1v) { b1v = lg[e]; i1 = e; }
      idxg[b * 2 + 0] = i0; idxg[b * 2 + 1] = i1;
      gvg[b * 2 + 0] = ex[i0] / sum; gvg[b * 2 + 1] = ex[i1] / sum;
    }
  }
}

// ---------------- histogram / scan / placement (LDS atomics only) ------------
__global__ __launch_bounds__(256) void hist_block(const int* __restrict__ idxg,
                                                  int* __restrict__ bc) {
  __shared__ int hloc[NEXP];
  const int t = threadIdx.x;
  if (t < NEXP) hloc[t] = 0;
  __syncthreads();
  int a = blockIdx.x * 256 + t;
  atomicAdd(&hloc[idxg[a]], 1);
  __syncthreads();
  if (t < NEXP) bc[blockIdx.x * NEXP + t] = hloc[t];
}

__global__ void scan_all(const int* __restrict__ bc, int* __restrict__ blockbase,
                         int* __restrict__ ntiles, int* __restrict__ te,
                         int* __restrict__ ts, int* __restrict__ tc,
                         float* __restrict__ loss_out) {
  __shared__ int counts[NEXP], basep[NEXP];
  const int t = threadIdx.x;
  if (t < NEXP) {
    int s = 0;
    for (int b = 0; b < 64; ++b) s += bc[b * NEXP + t];
    counts[t] = s;
  }
  __syncthreads();
  if (t == 0) {
    int acc = 0, nb = 0;
    for (int e = 0; e < NEXP; ++e) {
      basep[e] = acc;
      int c = counts[e];
      int nt = (c + 255) >> 8;
      for (int i = 0; i < nt; ++i) {
        te[nb] = e; ts[nb] = acc + i * 256; tc[nb] = min(256, c - i * 256); ++nb;
      }
      acc += c;
    }
    *ntiles = nb;
    *loss_out = 0.f;
  }
  __syncthreads();
  if (t < NEXP) {
    int run = basep[t];
    for (int b = 0; b < 64; ++b) { blockbase[b * NEXP + t] = run; run += bc[b * NEXP + t]; }
  }
}

__global__ __launch_bounds__(256) void place2(const int* __restrict__ idxg,
                                              const int* __restrict__ blockbase,
                                              int* __restrict__ token_list,
                                              int* __restrict__ slotmap) {
  __shared__ int cur[NEXP];
  const int t = threadIdx.x;
  if (t < NEXP) cur[t] = blockbase[blockIdx.x * NEXP + t];
  __syncthreads();
  int a = blockIdx.x * 256 + t;
  int e = idxg[a];
  int pos = atomicAdd(&cur[e], 1);
  token_list[pos] = a >> 1;
  slotmap[a] = pos;
}

// ---------------- int8 ternary MFMA GEMM (256x256 tile, BK=64, 16 waves) -----
// 16 waves x 64x64 out -> acc=64 VGPR/wave -> fits 128-reg bound -> 4 waves/SIMD.
// 64KB LDS (2 x 32KB dbuf); counted-vmcnt prefetch across raw barriers.
template <int KDIM, bool INDIRECT, bool RELU, bool FINAL>
__global__ __launch_bounds__(1024, 4) void gemm_i8(
    const int8_t* __restrict__ Aq, const int8_t* __restrict__ Wq,
    const float* __restrict__ swf_layer, const float* __restrict__ rcp_act,
    const float* __restrict__ bias, const int* __restrict__ te,
    const int* __restrict__ ts, const int* __restrict__ tc,
    const int* __restrict__ ntiles_p, const int* __restrict__ token_list,
    float* __restrict__ Yout, int Nvalid) {
  if ((int)blockIdx.x >= *ntiles_p) return;
  extern __shared__ __align__(16) int8_t smem_dyn[];   // 2 x 32KB: [A 16KB | B 16KB]
  const int t = blockIdx.x;
  const int e = te[t], row0 = ts[t], rcount = tc[t];
  const int col0 = blockIdx.y * 256;
  const int tid = threadIdx.x;
  const int lane = tid & 63, wid = tid >> 6;       // 16 waves
  const int wm = wid >> 2, wn = wid & 3;           // 4 (M) x 4 (N) -> 64x64 each

  // staging: 1024 chunk-positions per matrix (256 rows x 4 chunks of 16B)
  // LDS slot c holds global chunk c ^ ((r>>1)&3)  (pre-swizzled source)
  int p = tid, r = p >> 2, c = p & 3;
  int cs0 = c ^ ((r >> 1) & 3);
  int ar = row0 + min(r, rcount - 1);
  long arow = INDIRECT ? (long)token_list[ar] : (long)ar;
  const int8_t* srcA = Aq + arow * KDIM + cs0 * 16;
  int brr = min(col0 + r, Nvalid - 1);
  const int8_t* srcB = Wq + ((long)e * Nvalid + brr) * (long)KDIM + cs0 * 16;

  auto stage = [&](int buf, int kt) {
    int off = buf * 32768 + (wid << 10);           // wave base; lane*16 implicit
    load_lds16(srcA + kt * 64, &smem_dyn[off]);
    load_lds16(srcB + kt * 64, &smem_dyn[16384 + off]);
  };

  v4i acc[4][4] = {};
  constexpr int KT = KDIM / 64;
  stage(0, 0);
  asm volatile("s_waitcnt vmcnt(0)" ::: "memory");
  __builtin_amdgcn_s_barrier();
  int buf = 0;
  for (int kt = 0; kt < KT; ++kt) {
    if (kt + 1 < KT) {
      stage(buf ^ 1, kt + 1);                      // 2 loads stay in flight
      asm volatile("s_waitcnt vmcnt(2)" ::: "memory");
    } else {
      asm volatile("s_waitcnt vmcnt(0)" ::: "memory");
    }
    __builtin_amdgcn_s_barrier();
    __builtin_amdgcn_sched_barrier(0);
    const int8_t* As = &smem_dyn[buf * 32768];
    const int8_t* Bs = &smem_dyn[buf * 32768 + 16384];
    v4i bv[4];
#pragma unroll
    for (int n = 0; n < 4; ++n) {
      int rr = wn * 64 + n * 16 + (lane & 15);
      int cs = (lane >> 4) ^ ((rr >> 1) & 3);
      bv[n] = *(const v4i*)&Bs[rr * 64 + cs * 16];
    }
#pragma unroll
    for (int m = 0; m < 4; ++m) {
      int rr = wm * 64 + m * 16 + (lane & 15);
      int cs = (lane >> 4) ^ ((rr >> 1) & 3);
      v4i av = *(const v4i*)&As[rr * 64 + cs * 16];
#pragma unroll
      for (int n = 0; n < 4; ++n)
        acc[m][n] = __builtin_amdgcn_mfma_i32_16x16x64_i8(av, bv[n], acc[m][n], 0, 0, 0);
    }
    __builtin_amdgcn_sched_barrier(0);
    __builtin_amdgcn_s_barrier();
    buf ^= 1;
  }

  const float sw = swf_layer[e];
  const int rbase = (lane >> 4) * 4;
  const int cfr = lane & 15;
  const float* bias_e = bias + (long)e * Nvalid;
#pragma unroll
  for (int m = 0; m < 4; ++m) {
#pragma unroll
    for (int rg = 0; rg < 4; ++rg) {
      int trow = wm * 64 + m * 16 + rbase + rg;
      if (trow >= rcount) continue;
      int slot = row0 + trow;
      float rcp = rcp_act[INDIRECT ? token_list[slot] : slot];
      float dq = sw * rcp;
      if (!FINAL) {
        float* yrow = Yout + (long)slot * 2048;
#pragma unroll
        for (int n = 0; n < 4; ++n) {
          int o = col0 + wn * 64 + n * 16 + cfr;
          float v = (float)acc[m][n][rg] * dq + bias_e[o];
          if (RELU) v = fmaxf(v, 0.f);
          yrow[o] = v;
        }
      } else {
        float* zrow = Yout + (long)slot * 1024;
#pragma unroll
        for (int n = 0; n < 4; ++n) {
          int o = col0 + wn * 64 + n * 16 + cfr;
          float bb = bias_e[min(o, Nvalid - 1)];
          zrow[o] = (float)acc[m][n][rg] * dq + bb;
        }
      }
    }
  }
}

// ---------------- gate-weighted combine: out[b] = g0*z[s0] + g1*z[s1] --------
__global__ __launch_bounds__(256) void combine(const float* __restrict__ z,
                                               const int* __restrict__ slotmap,
                                               const float* __restrict__ gvg,
                                               float* __restrict__ out) {
  const int b = blockIdx.x;
  const int c = threadIdx.x;
  if (c >= 250) return;
  const int s0 = slotmap[b * 2], s1 = slotmap[b * 2 + 1];
  const float g0 = gvg[b * 2] * 0.5f, g1 = gvg[b * 2 + 1] * 0.5f;
  float4 a = *(const float4*)(z + (long)s0 * 1024 + c * 4);
  float4 q = *(const float4*)(z + (long)s1 * 1024 + c * 4);
  float4 o = {g0 * a.x + g1 * q.x, g0 * a.y + g1 * q.y,
              g0 * a.z + g1 * q.z, g0 * a.w + g1 * q.w};
  *(float4*)(out + (long)b * CDIM + c * 4) = o;
}

// ---------------- host launcher ----------------------------------------------
extern "C" void kernel_launch(void* const* d_in, const int* in_sizes, int n_in,
                              void* d_out, int out_size, void* d_ws, size_t ws_size,
                              hipStream_t stream) {
  const float* x   = (const float*)d_in[0];
  const float* Wr1 = (const float*)d_in[1];
  const float* br1 = (const float*)d_in[2];
  const float* Wr2 = (const float*)d_in[3];
  const float* br2 = (const float*)d_in[4];
  const float* W1  = (const float*)d_in[5];
  const float* b1  = (const float*)d_in[6];
  const float* W2  = (const float*)d_in[7];
  const float* b2  = (const float*)d_in[8];
  const float* W3  = (const float*)d_in[9];
  const float* b3  = (const float*)d_in[10];
  float* out = (float*)d_out;
  char* ws = (char*)d_ws;

  size_t off = 0;
  auto alloc = [&](size_t sz) { size_t r = off; off = (off + sz + 255) & ~(size_t)255; return r; };
  size_t O_META  = alloc(8192);
  size_t O_SUSP  = alloc(B_T * sizeof(int));
  size_t O_PART  = alloc(24 * 32 * sizeof(double));
  size_t O_SWF   = alloc(24 * sizeof(float));
  size_t O_RCPX  = alloc(B_T * sizeof(float));
  size_t O_IDX   = alloc(B_T * 2 * sizeof(int));
  size_t O_GVG   = alloc(B_T * 2 * sizeof(float));
  size_t O_TLIST = alloc(NSLOT * sizeof(int));
  size_t O_SLOT  = alloc(B_T * 2 * sizeof(int));
  size_t O_S1    = alloc(NSLOT * sizeof(float));
  size_t O_S2    = alloc(NSLOT * sizeof(float));
  size_t O_XQ    = alloc((size_t)B_T * IN_D);
  size_t O_WQ1   = alloc((size_t)NEXP * H1D * IN_D);
  size_t O_WQ2   = alloc((size_t)NEXP * H2D * H1D);
  size_t O_WQ3   = alloc((size_t)NEXP * CDIM * H2D);
  size_t O_YQ    = alloc((size_t)NSLOT * 2048);
  size_t O_YBIG  = alloc((size_t)NSLOT * 2048 * sizeof(float));
  (void)ws_size; (void)in_sizes; (void)n_in;

  int*    te     = (int*)(ws + O_META);
  int*    tsv    = te + 144;
  int*    tcv    = tsv + 144;
  int*    ntiles = tcv + 144;
  int*    bc     = ntiles + 4;          // 64*8
  int*    bbase  = bc + 512;            // 64*8
  int*    scount = bbase + 512;
  int*    susp   = (int*)(ws + O_SUSP);
  double* part   = (double*)(ws + O_PART);
  float*  swf    = (float*)(ws + O_SWF);
  float*  rcpx   = (float*)(ws + O_RCPX);
  int*    idxg   = (int*)(ws + O_IDX);
  float*  gvg    = (float*)(ws + O_GVG);
  int*    tlist  = (int*)(ws + O_TLIST);
  int*    slotmap= (int*)(ws + O_SLOT);
  float*  s1     = (float*)(ws + O_S1);
  float*  s2     = (float*)(ws + O_S2);
  int8_t* Xq     = (int8_t*)(ws + O_XQ);
  int8_t* wq1    = (int8_t*)(ws + O_WQ1);
  int8_t* wq2    = (int8_t*)(ws + O_WQ2);
  int8_t* wq3    = (int8_t*)(ws + O_WQ3);
  int8_t* Yq     = (int8_t*)(ws + O_YQ);
  float*  Ybig   = (float*)(ws + O_YBIG);   // router h; split bufs; activations; z
  float*  h      = Ybig;
  float*  zbuf   = Ybig;

  // bf16 split buffers live in the (currently dead) tail of Ybig
  char* ybytes = (char*)Ybig;
  uint16_t* xh = (uint16_t*)(ybytes + (20l << 20));
  uint16_t* xl = (uint16_t*)(ybytes + (40l << 20));
  uint16_t* wh = (uint16_t*)(ybytes + (60l << 20));
  uint16_t* wl = (uint16_t*)(ybytes + (62l << 20));

  hipMemsetAsync(ws + O_META, 0, 8192, stream);

  // weight scales + ternary quant
  wabs_reduce<<<dim3(32, 8), 256, 0, stream>>>(W1, (long)H1D * IN_D, 0, part);
  wabs_reduce<<<dim3(32, 8), 256, 0, stream>>>(W2, (long)H2D * H1D, 8, part);
  wabs_reduce<<<dim3(32, 8), 256, 0, stream>>>(W3, (long)CDIM * H2D, 16, part);
  finalize_scales<<<1, 64, 0, stream>>>(part, swf);
  wquant<<<16384, 256, 0, stream>>>(W1, wq1, swf, 0, (long)H1D * IN_D, 4194304L);
  wquant<<<32768, 256, 0, stream>>>(W2, wq2, swf, 8, (long)H2D * H1D, 8388608L);
  wquant<<<16000, 256, 0, stream>>>(W3, wq3, swf, 16, (long)CDIM * H2D, 4096000L);

  // activation quant of x
  actquant<IN_D><<<B_T, 256, 0, stream>>>(x, Xq, rcpx);

  // router: split -> bf16x3 MFMA -> stage2 -> gap-guard fixup
  split_bf16<<<8192, 256, 0, stream>>>(x, xh, xl, (long)B_T * IN_D / 4);
  split_bf16<<<512, 256, 0, stream>>>(Wr1, wh, wl, (long)RHD * IN_D / 4);
  router_mfma<<<dim3(B_T / 128, RHD / 128), 256, 0, stream>>>(xh, xl, wh, wl, br1, h);
  router_stage2<<<B_T / 4, 256, 0, stream>>>(h, Wr2, br2, out + (size_t)B_T * CDIM,
                                             idxg, gvg, scount, susp);
  router_fixup<<<128, 256, 0, stream>>>(x, Wr1, br1, Wr2, br2, susp, scount,
                                        out + (size_t)B_T * CDIM, idxg, gvg);
  hist_block<<<64, 256, 0, stream>>>(idxg, bc);
  scan_all<<<1, 64, 0, stream>>>(bc, bbase, ntiles, te, tsv, tcv,
                                 out + (size_t)B_T * CDIM + (size_t)B_T * NEXP);
  place2<<<64, 256, 0, stream>>>(idxg, bbase, tlist, slotmap);

  // expert layers (int8 MFMA, 256x256 tiles, 16 waves, 64KB dynamic LDS)
  gemm_i8<IN_D, true, true, false><<<dim3(MAXT, H1D / 256), 1024, 65536, stream>>>(
      Xq, wq1, swf + 0, rcpx, b1, te, tsv, tcv, ntiles, tlist, Ybig, H1D);
  actquant<2048><<<NSLOT, 256, 0, stream>>>(Ybig, Yq, s1);
  gemm_i8<2048, false, true, false><<<dim3(MAXT, H2D / 256), 1024, 65536, stream>>>(
      Yq, wq2, swf + 8, s1, b2, te, tsv, tcv, ntiles, tlist, Ybig, H2D);
  actquant<2048><<<NSLOT, 256, 0, stream>>>(Ybig, Yq, s2);
  gemm_i8<2048, false, false, true><<<dim3(MAXT, 1024 / 256), 1024, 65536, stream>>>(
      Yq, wq3, swf + 16, s2, b3, te, tsv, tcv, ntiles, tlist, zbuf, CDIM);

  // gate-weighted combine into d_out
  combine<<<B_T, 256, 0, stream>>>(zbuf, slotmap, gvg, out);
}